// Round 5
// baseline (239.598 us; speedup 1.0000x reference)
//
#include <hip/hip_runtime.h>
#include <hip/hip_bf16.h>
#include <stdint.h>

// B=256 batches, T=256 seq, D=512 embed, HD=64 head dim
#define NB 256
#define NT 256
#define ND 512
#define NH 64

typedef __bf16 bf16;
typedef __bf16 bf16x4 __attribute__((ext_vector_type(4)));
typedef __bf16 bf16x8 __attribute__((ext_vector_type(8)));
typedef float f32x4 __attribute__((ext_vector_type(4)));

static __device__ __forceinline__ f32x4 mfma16(bf16x8 a, bf16x8 b, f32x4 c) {
    return __builtin_amdgcn_mfma_f32_16x16x32_bf16(a, b, c, 0, 0, 0);
}

static __device__ __forceinline__ bf16x8 cvt8(f32x4 a, f32x4 b) {
    bf16x8 r;
    r[0] = (bf16)a.x; r[1] = (bf16)a.y; r[2] = (bf16)a.z; r[3] = (bf16)a.w;
    r[4] = (bf16)b.x; r[5] = (bf16)b.y; r[6] = (bf16)b.z; r[7] = (bf16)b.w;
    return r;
}

// async global->LDS, 16B per lane; dst is the wave-uniform base (HW adds lane*16)
static __device__ __forceinline__ void gload_lds16(const void* g, void* l) {
    __builtin_amdgcn_global_load_lds(
        (const __attribute__((address_space(1))) void*)g,
        (__attribute__((address_space(3))) void*)l, 16, 0, 0);
}

// ---------------- Kernel 0: W fp32 -> bf16, packed [192][512] (q 0-63, k 64-127, v 128-191)
__global__ __launch_bounds__(256) void wconv_kernel(
        const float* __restrict__ Wq, const float* __restrict__ Wk,
        const float* __restrict__ Wv, bf16* __restrict__ wbf) {
    int idx = (blockIdx.x * 256 + threadIdx.x) * 4;
    const float* src;
    if (idx < 64 * ND)       src = Wq + idx;
    else if (idx < 128 * ND) src = Wk + (idx - 64 * ND);
    else                     src = Wv + (idx - 128 * ND);
    f32x4 v = *reinterpret_cast<const f32x4*>(src);
    bf16x4 o;
    o[0] = (bf16)v.x; o[1] = (bf16)v.y; o[2] = (bf16)v.z; o[3] = (bf16)v.w;
    *reinterpret_cast<bf16x4*>(wbf + idx) = o;
}

// ---------------- Kernel 1: fused q/k/v projection GEMM (pipelined)
// 1024 blocks x 256 thr (4 waves). BM=64; wave w owns cols 48w..48w+47 of [q|k|v].
// x staged fp32 via global_load_lds into 3 LDS buffers (16KB each), depth-2 prefetch,
// counted s_waitcnt vmcnt(4) + raw s_barrier (never drain-to-0 in loop). W B-frags
// register-prefetched one step ahead (issued BEFORE the DMAs so compiler W-waits
// leave the youngest 4 DMAs in flight). Source addrs pre-XOR-swizzled (row&7)<<4.
__global__ __launch_bounds__(256, 3) void qkv_gemm_kernel(
        const float* __restrict__ x, const bf16* __restrict__ wbf,
        bf16* __restrict__ qws, bf16* __restrict__ kws, bf16* __restrict__ vt) {
    __shared__ alignas(16) char lds[49152];   // 3 x (64 rows x 256B fp32)
    const int t = threadIdx.x, lane = t & 63, wave = t >> 6;
    const int l15 = lane & 15, g = lane >> 4;
    const long m0 = (long)blockIdx.x * 64;
    const char* xb = (const char*)x;

    f32x4 acc[4][3] = {};
    bf16x8 Wcur[6], Wnxt[6];   // [ci*2 + k2]

    auto stageDMA = [&](int s) {   // 4 DMA: tile s -> buf s%3
        char* base = lds + (s % 3) * 16384;
        #pragma unroll
        for (int i = 0; i < 4; ++i) {
            int row = wave * 16 + i * 4 + g;
            const char* src = xb + (m0 + row) * 2048 + (long)s * 256
                            + ((l15 * 16) ^ ((row & 7) << 4));
            gload_lds16(src, base + (wave * 4 + i) * 1024);
        }
    };
    auto loadW = [&](int s, bf16x8* Wr) {
        #pragma unroll
        for (int ci = 0; ci < 3; ++ci) {
            int n = wave * 48 + ci * 16 + l15;
            const bf16* wsrc = wbf + n * ND + s * 64 + g * 8;
            Wr[ci * 2 + 0] = *reinterpret_cast<const bf16x8*>(wsrc);
            Wr[ci * 2 + 1] = *reinterpret_cast<const bf16x8*>(wsrc + 32);
        }
    };

    // prologue: W(0) first, then DMA(0), DMA(1)
    loadW(0, Wcur);
    stageDMA(0);
    stageDMA(1);
    asm volatile("s_waitcnt vmcnt(4)" ::: "memory");  // W(0)+DMA(0) done; DMA(1) flying
    __builtin_amdgcn_s_barrier();

    #pragma unroll
    for (int s = 0; s < 8; ++s) {
        if (s < 7) loadW(s + 1, Wnxt);     // issue before DMAs (FIFO vmcnt math)
        if (s < 6) stageDMA(s + 2);
        // compute tile s from buf s%3
        char* cbuf = lds + (s % 3) * 16384;
        #pragma unroll
        for (int k2 = 0; k2 < 2; ++k2) {
            const int cbyte = (k2 * 32 + g * 8) * 4;
            bf16x8 Af[4];
            #pragma unroll
            for (int ri = 0; ri < 4; ++ri) {
                int row = ri * 16 + l15;
                int sw = (row & 7) << 4;
                f32x4 lo = *reinterpret_cast<const f32x4*>(cbuf + row * 256 + (cbyte ^ sw));
                f32x4 hi = *reinterpret_cast<const f32x4*>(cbuf + row * 256 + ((cbyte + 16) ^ sw));
                Af[ri] = cvt8(lo, hi);
            }
            #pragma unroll
            for (int ci = 0; ci < 3; ++ci) {
                #pragma unroll
                for (int ri = 0; ri < 4; ++ri)
                    acc[ri][ci] = mfma16(Af[ri], Wcur[ci * 2 + k2], acc[ri][ci]);
            }
        }
        if (s < 7) {
            #pragma unroll
            for (int i = 0; i < 6; ++i) Wcur[i] = Wnxt[i];
            // leave only the youngest 4 (next-next DMA) in flight
            asm volatile("s_waitcnt vmcnt(4)" ::: "memory");
            __builtin_amdgcn_s_barrier();
            asm volatile("" ::: "memory");
        }
    }

    // epilogue: q scaled by 0.125; v transposed per batch vt[b][hd][t]
    const int b = blockIdx.x >> 2;
    const int tb = (blockIdx.x & 3) * 64;
    #pragma unroll
    for (int ci = 0; ci < 3; ++ci) {
        int n = wave * 48 + ci * 16 + l15;
        int sel = n >> 6, hd = n & 63;
        #pragma unroll
        for (int ri = 0; ri < 4; ++ri) {
            #pragma unroll
            for (int r = 0; r < 4; ++r) {
                int trow = tb + ri * 16 + g * 4 + r;
                long grow = m0 + ri * 16 + g * 4 + r;
                float val = acc[ri][ci][r];
                if (sel == 0)      qws[grow * NH + hd] = (bf16)(val * 0.125f);
                else if (sel == 1) kws[grow * NH + hd] = (bf16)val;
                else               vt[((long)b * NH + hd) * NT + trow] = (bf16)val;
            }
        }
    }
}

// ---------------- Kernel 2: causal attention
// grid (4, NB) x 256 thr: block = (64-row q-block qb, batch b); wave w owns 16-row
// tile qt = 4qb+w. LDS 36KB: K prefix [KV][64] bf16 @0 (<=32KB, XOR-swizzled, staged
// once, shared) + per-wave P chunk [16][32] @32768+w*1024 (XOR key (row>>2)&3).
// V^T direct from global (L3-hot). 4 blocks/CU -> 16 waves/CU.
__global__ __launch_bounds__(256, 4) void attn_kernel(
        const bf16* __restrict__ qws, const bf16* __restrict__ kws,
        const bf16* __restrict__ vt, float* __restrict__ out) {
    __shared__ alignas(16) char lds[36864];
    const int t = threadIdx.x, lane = t & 63, wave = t >> 6;
    const int l15 = lane & 15, g = lane >> 4;
    const int qb = blockIdx.x, b = blockIdx.y;
    const long bbase = (long)b * NT;
    const int KV = (qb + 1) * 64;

    // stage K rows [0, KV): thread t -> row t (128B, swizzled (row&7)<<4)
    if (t < KV) {
        const bf16* src = kws + (bbase + t) * NH;
        char* dstrow = lds + t * 128;
        int sw = (t & 7) << 4;
        #pragma unroll
        for (int j = 0; j < 8; ++j) {
            bf16x8 v = *reinterpret_cast<const bf16x8*>(src + j * 8);
            *reinterpret_cast<bf16x8*>(dstrow + ((j * 16) ^ sw)) = v;
        }
    }
    __syncthreads();

    const int qt = qb * 4 + wave;
    const int nct = qt + 1, nch = (nct + 1) >> 1;
    char* plds = lds + 32768 + wave * 1024;

    bf16x8 Qf0, Qf1;
    {
        const bf16* qsrc = qws + (bbase + qt * 16 + l15) * NH + g * 8;
        Qf0 = *reinterpret_cast<const bf16x8*>(qsrc);
        Qf1 = *reinterpret_cast<const bf16x8*>(qsrc + 32);
    }
    const int qrow0 = qt * 16 + g * 4;
    float sum[4] = {0.f, 0.f, 0.f, 0.f};
    f32x4 O[4] = {};

    for (int ch = 0; ch < nch; ++ch) {
        const int c0 = ch * 32 + l15, c1 = c0 + 16;
        const bool t1v = (2 * ch + 1) < nct;
        f32x4 S0 = {}, S1 = {};
        {
            const char* k0p = lds + c0 * 128;
            int sw0 = (c0 & 7) << 4;
            S0 = mfma16(Qf0, *reinterpret_cast<const bf16x8*>(k0p + ((g * 16) ^ sw0)), S0);
            S0 = mfma16(Qf1, *reinterpret_cast<const bf16x8*>(k0p + ((64 + g * 16) ^ sw0)), S0);
            if (t1v) {
                const char* k1p = lds + c1 * 128;
                int sw1 = (c1 & 7) << 4;
                S1 = mfma16(Qf0, *reinterpret_cast<const bf16x8*>(k1p + ((g * 16) ^ sw1)), S1);
                S1 = mfma16(Qf1, *reinterpret_cast<const bf16x8*>(k1p + ((64 + g * 16) ^ sw1)), S1);
            }
        }
        // mask + exp + row-sum + P chunk write (bf16; [16 rows][32 cols], stride 64B,
        // byte = row*64 + ((2*col) ^ (((row>>2)&3)<<4)) -> 2-way write banks (free))
        #pragma unroll
        for (int r = 0; r < 4; ++r) {
            int rowp = g * 4 + r;
            int key = ((rowp >> 2) & 3) << 4;
            float p0 = (c0 <= qrow0 + r) ? __expf(S0[r]) : 0.0f;
            sum[r] += p0;
            *reinterpret_cast<bf16*>(plds + rowp * 64 + ((2 * l15) ^ key)) = (bf16)p0;
            float p1 = (t1v && c1 <= qrow0 + r) ? __expf(S1[r]) : 0.0f;
            sum[r] += p1;
            *reinterpret_cast<bf16*>(plds + rowp * 64 + ((2 * (l15 + 16)) ^ key)) = (bf16)p1;
        }
        // PV for this 32-k chunk: P A-frag from LDS, V^T B-frag from global
        bf16x8 Pf = *reinterpret_cast<const bf16x8*>(
            plds + l15 * 64 + ((g * 16) ^ (((l15 >> 2) & 3) << 4)));
        const int k0 = ch * 32 + g * 8;
        #pragma unroll
        for (int cb2 = 0; cb2 < 4; ++cb2) {
            int hd = cb2 * 16 + l15;
            bf16x8 Vf = *reinterpret_cast<const bf16x8*>(
                vt + ((long)b * NH + hd) * NT + k0);
            O[cb2] = mfma16(Pf, Vf, O[cb2]);
        }
    }

    #pragma unroll
    for (int r = 0; r < 4; ++r) {
        sum[r] += __shfl_xor(sum[r], 1);
        sum[r] += __shfl_xor(sum[r], 2);
        sum[r] += __shfl_xor(sum[r], 4);
        sum[r] += __shfl_xor(sum[r], 8);
        sum[r] = 1.0f / sum[r];
    }
    #pragma unroll
    for (int cb2 = 0; cb2 < 4; ++cb2) {
        int hd = cb2 * 16 + l15;
        #pragma unroll
        for (int r = 0; r < 4; ++r) {
            long orow = bbase + qt * 16 + g * 4 + r;
            out[orow * NH + hd] = O[cb2][r] * sum[r];
        }
    }
}

// ---------------- launch
extern "C" void kernel_launch(void* const* d_in, const int* in_sizes, int n_in,
                              void* d_out, int out_size, void* d_ws, size_t ws_size,
                              hipStream_t stream) {
    const float* x  = (const float*)d_in[0];
    const float* Wq = (const float*)d_in[1];
    const float* Wk = (const float*)d_in[2];
    const float* Wv = (const float*)d_in[3];
    float* out = (float*)d_out;

    // ws layout: wbf [192][512] bf16 (192KB), then q [B*T][64], k [B*T][64], vt [B][64][T] bf16.
    char* ws = (char*)d_ws;
    bf16* wbf = (bf16*)ws;
    bf16* qws = (bf16*)(ws + 0x30000);
    bf16* kws = (bf16*)(ws + 0x30000 + 8388608);
    bf16* vt  = (bf16*)(ws + 0x30000 + 2 * 8388608);

    wconv_kernel<<<96, 256, 0, stream>>>(Wq, Wk, Wv, wbf);
    qkv_gemm_kernel<<<1024, 256, 0, stream>>>(x, wbf, qws, kws, vt);
    attn_kernel<<<dim3(4, NB), 256, 0, stream>>>(qws, kws, vt, out);
}